// Round 14
// baseline (310.843 us; speedup 1.0000x reference)
//
#include <hip/hip_runtime.h>
#include <hip/hip_bf16.h>

// GCN on MI355X — 6 launches:
//   K1 setup      : cursors init + deg zero + W1,W2 -> bf16 W^T
//   K2 bin8       : split by dst>>13 into 7 super-buckets, uint2{src,dst};
//                   long runs (~3.5KB) vs R12's 64B runs. + deg[] histogram.
//   K3 subsort    : super regions -> 196 final buckets (pay = src|dl<<24)
//   K4 build_gemm1: blocks<196 build CSR ∥ rest gemm1 (di from deg), 2 tiles/blk
//   K5 agg_gemm2  : a1 = relu(di*(self+Σh1')+b1) -> LDS; h2' = dinv⊙(a1@W2)
//   K6 agg_out    : a2 = relu(di*(self+Σh2')+b2); out = a2@Wc + bc
// R13 CRASHED: SCAP was set to the EXACT per-region mean (262144) -> ~50% of
// regions overflowed, spilled edges corrupted neighbors, final buckets
// overflowed CAP, OOB store. Fix: SCAP = mean + 16384 (~35 sigma).
// Aggregate: one NODE per 16-lane quarter, 8-edge unrolled unmasked loop +
// compensated masked tail; h pre-scaled by dinv (GCN norm identity).
// h bf16; accumulation fp32. Requires n <= 65536.

typedef unsigned int uint;
typedef unsigned short ushort;
typedef __attribute__((ext_vector_type(8))) short bf16x8;
typedef __attribute__((ext_vector_type(4))) float f32x4;

#define NPB 256
#define CAP 12288      // edges per final bucket region; mean 8192, sd ~90
#define SCAP 278528    // edges per super region; full-bucket mean 262144 + 35σ
#define SBLK 73        // subsort blocks per super-bucket

static __device__ __forceinline__ ushort f2bf(float f) {
    unsigned u = __float_as_uint(f);
    u += 0x7fffu + ((u >> 16) & 1u);   // round-to-nearest-even
    return (ushort)(u >> 16);
}
static __device__ __forceinline__ uint pack2(float a, float b) {
    return (uint)f2bf(a) | ((uint)f2bf(b) << 16);
}
static __device__ __forceinline__ float lo2f(uint u) { return __uint_as_float(u << 16); }
static __device__ __forceinline__ float hi2f(uint u) { return __uint_as_float(u & 0xffff0000u); }

#define UNPACK8(dst, u)                                        \
    dst[0] = lo2f(u.x); dst[1] = hi2f(u.x);                    \
    dst[2] = lo2f(u.y); dst[3] = hi2f(u.y);                    \
    dst[4] = lo2f(u.z); dst[5] = hi2f(u.z);                    \
    dst[6] = lo2f(u.w); dst[7] = hi2f(u.w);

// ---------------- K1: setup ----------------
__global__ __launch_bounds__(256) void setup(int* __restrict__ bcursor,
                                             int* __restrict__ bcursor8,
                                             int* __restrict__ deg,
                                             const float* __restrict__ W1,
                                             const float* __restrict__ W2,
                                             ushort* __restrict__ Wt1,
                                             ushort* __restrict__ Wt2,
                                             int n, int nbuckets, int nsb) {
    int gid = blockIdx.x * 256 + threadIdx.x;     // grid 64*256 = 16384
    if (gid < nbuckets) bcursor[gid] = gid * CAP;
    if (gid < nsb) bcursor8[gid] = gid * SCAP;
    for (int i = gid; i < n; i += 64 * 256) deg[i] = 0;
    {   // 128x128 transpose to [n][k] bf16
        int k = gid >> 7, nn = gid & 127;
        Wt1[nn * 128 + k] = f2bf(W1[gid]);
        Wt2[nn * 128 + k] = f2bf(W2[gid]);
    }
}

// ---------------- K2: bin8 — 7-way super split + deg histogram ----------------
__global__ __launch_bounds__(1024) void bin8(const int* __restrict__ src,
                                             const int* __restrict__ dst,
                                             int* __restrict__ bcursor8,
                                             int* __restrict__ deg,
                                             uint2* __restrict__ pay8,
                                             int E) {
    __shared__ int cnt[8];
    __shared__ int base[8];
    int tid = threadIdx.x;
    if (tid < 8) cnt[tid] = 0;
    __syncthreads();
    int chunk = (E + gridDim.x - 1) / gridDim.x;
    int i0 = blockIdx.x * chunk;
    int i1 = min(E, i0 + chunk);
    for (int i = i0 + tid; i < i1; i += 1024) {
        int d = dst[i];
        atomicAdd(&cnt[d >> 13], 1);
        atomicAdd(&deg[d], 1);       // 200KB array: L2-resident atomics
    }
    __syncthreads();
    if (tid < 8) base[tid] = cnt[tid] ? atomicAdd(&bcursor8[tid], cnt[tid]) : 0;
    __syncthreads();
    if (tid < 8) cnt[tid] = 0;
    __syncthreads();
    for (int i = i0 + tid; i < i1; i += 1024) {
        int d = dst[i];
        int b = d >> 13;
        int pos = base[b] + atomicAdd(&cnt[b], 1);
        pay8[pos] = make_uint2((uint)src[i], (uint)d);
    }
}

// ---------------- K3: subsort — super regions -> 196 final buckets ----------------
__global__ __launch_bounds__(512) void subsort(const uint2* __restrict__ pay8,
                                               const int* __restrict__ bcursor8,
                                               int* __restrict__ bcursor,
                                               uint* __restrict__ pay, int nsb) {
    __shared__ int cnt[32];
    __shared__ int base[32];
    int tid = threadIdx.x;
    int sb = blockIdx.x / SBLK;
    int blk = blockIdx.x % SBLK;
    if (sb >= nsb) return;
    int s0 = sb * SCAP;
    int e0 = bcursor8[sb];
    int csb = e0 - s0;
    int chunk = (csb + SBLK - 1) / SBLK;
    int i0 = s0 + blk * chunk;
    int i1 = min(e0, i0 + chunk);
    if (tid < 32) cnt[tid] = 0;
    __syncthreads();
    for (int i = i0 + tid; i < i1; i += 512)
        atomicAdd(&cnt[(pay8[i].y >> 8) & 31], 1);
    __syncthreads();
    if (tid < 32) {
        int gb = sb * 32 + tid;   // == dst>>8 (global final bucket)
        base[tid] = cnt[tid] ? atomicAdd(&bcursor[gb], cnt[tid]) : 0;
    }
    __syncthreads();
    if (tid < 32) cnt[tid] = 0;
    __syncthreads();
    for (int i = i0 + tid; i < i1; i += 512) {
        uint2 p = pay8[i];
        int lb = (p.y >> 8) & 31;
        int pos = base[lb] + atomicAdd(&cnt[lb], 1);
        pay[pos] = p.x | ((p.y & 255u) << 24);
    }
}

// ---------------- K4: build_rows ∥ gemm1 (dual-role, 512 threads) ----------------
__global__ __launch_bounds__(512) void build_gemm1(const uint* __restrict__ pay,
                                                   const int* __restrict__ bcursor,
                                                   int* __restrict__ rowstart,
                                                   int* __restrict__ rowend,
                                                   float* __restrict__ dinv,
                                                   int* __restrict__ colidx,
                                                   const float* __restrict__ x,
                                                   const ushort* __restrict__ Wt1,
                                                   const int* __restrict__ deg,
                                                   uint* __restrict__ bufA,
                                                   int n, int nbuckets, int ntile) {
    __shared__ int s_hist[256];
    __shared__ int s_sc[256];
    __shared__ int s_cur[256];
    __shared__ __align__(16) ushort sOut[8][16][136];  // 34.8 KB
    int tid = threadIdx.x;

    if ((int)blockIdx.x < nbuckets) {
        // ---- build_rows ----
        int b = blockIdx.x;
        int node0 = b * NPB;
        int s = b * CAP, e = bcursor[b];
        if (tid < 256) s_hist[tid] = 0;
        __syncthreads();
        for (int i = s + tid; i < e; i += 512) atomicAdd(&s_hist[pay[i] >> 24], 1);
        __syncthreads();
        int v = (tid < 256) ? s_hist[tid] : 0;
        if (tid < 256) s_sc[tid] = v;
        __syncthreads();
        for (int d = 1; d < 256; d <<= 1) {
            int xx = (tid < 256 && tid >= d) ? s_sc[tid - d] : 0;
            __syncthreads();
            if (tid < 256) s_sc[tid] += xx;
            __syncthreads();
        }
        if (tid < 256) {
            int excl = s_sc[tid] - v;
            s_cur[tid] = s + excl;
            int node = node0 + tid;
            if (node < n) {
                rowstart[node] = s + excl;
                rowend[node] = s + excl + v;
                dinv[node] = rsqrtf((float)(v + 1));  // +1 self-loop
            }
        }
        __syncthreads();
        for (int i = s + tid; i < e; i += 512) {
            uint pp = pay[i];
            int pos = atomicAdd(&s_cur[pp >> 24], 1);
            colidx[pos] = (int)(pp & 0xffffffu);
        }
    } else {
        // ---- gemm1: h1' = rsqrt(deg+1) ⊙ (x@W1), bf16 out; 2 tiles/block ----
        const int wave = tid >> 6;          // 0..7
        const int lane = tid & 63;
        const int quad = lane >> 4, l16 = lane & 15;
        const int tile = ((int)blockIdx.x - nbuckets) * 2 + (wave >> 2);
        const int m0 = tile * 64 + (wave & 3) * 16;
        bool active = tile < ntile;

        if (active) {
            f32x4 acc[8];
#pragma unroll
            for (int i = 0; i < 8; ++i) acc[i] = (f32x4){0.f, 0.f, 0.f, 0.f};

            int arow = m0 + l16;
            arow = arow < n ? arow : n - 1;

#pragma unroll
            for (int ks = 0; ks < 4; ++ks) {
                const float* px = &x[(size_t)arow * 128 + ks * 32 + quad * 8];
                float4 x0 = *(const float4*)px;
                float4 x1 = *(const float4*)(px + 4);
                ushort av[8] = {f2bf(x0.x), f2bf(x0.y), f2bf(x0.z), f2bf(x0.w),
                                f2bf(x1.x), f2bf(x1.y), f2bf(x1.z), f2bf(x1.w)};
                bf16x8 a = *(const bf16x8*)av;
#pragma unroll
                for (int nt = 0; nt < 8; ++nt) {
                    bf16x8 b = *(const bf16x8*)&Wt1[(size_t)(nt * 16 + l16) * 128 + ks * 32 + quad * 8];
                    acc[nt] = __builtin_amdgcn_mfma_f32_16x16x32_bf16(a, b, acc[nt], 0, 0, 0);
                }
            }

            float dv[4];
#pragma unroll
            for (int r = 0; r < 4; ++r) {
                int rr = m0 + quad * 4 + r;
                dv[r] = rsqrtf((float)(deg[rr < n ? rr : n - 1] + 1));
            }
#pragma unroll
            for (int nt = 0; nt < 8; ++nt)
#pragma unroll
                for (int r = 0; r < 4; ++r)
                    sOut[wave][quad * 4 + r][nt * 16 + l16] = f2bf(acc[nt][r] * dv[r]);
        }
        __syncthreads();

        if (active) {
#pragma unroll
            for (int i = 0; i < 4; ++i) {
                int linear = i * 64 + lane;
                int row = linear >> 4, chunk = linear & 15;
                int rr = m0 + row;
                if (rr < n) {
                    uint4 v = *(const uint4*)&sOut[wave][row][chunk * 8];
                    *(uint4*)&bufA[(size_t)rr * 64 + chunk * 4] = v;
                }
            }
        }
    }
}

// ---- aggregate gather: one node per 16-lane quarter, 8-edge unrolled ----
static __device__ __forceinline__ void gather_q(const uint4* __restrict__ H4,
                                                int s, int e, int nn, int sub,
                                                const int* __restrict__ colidx,
                                                float acc[8]) {
    uint4 su = H4[(size_t)nn * 16 + sub];
    float t[8];
    UNPACK8(t, su);
#pragma unroll
    for (int j = 0; j < 8; ++j) acc[j] = t[j];   // self term (pre-scaled h')

    int p = s;
    for (; p + 8 <= e; p += 8) {
        int c[8];
#pragma unroll
        for (int i = 0; i < 8; ++i) c[i] = colidx[p + i];
        uint4 u[8];
#pragma unroll
        for (int i = 0; i < 8; ++i) u[i] = H4[(size_t)c[i] * 16 + sub];
#pragma unroll
        for (int i = 0; i < 8; ++i) {
            float a[8];
            UNPACK8(a, u[i]);
#pragma unroll
            for (int j = 0; j < 8; ++j) acc[j] += a[j];
        }
    }
    if (p < e) {
        int c[8];
#pragma unroll
        for (int i = 0; i < 8; ++i) c[i] = (p + i < e) ? colidx[p + i] : nn;
        uint4 u[8];
#pragma unroll
        for (int i = 0; i < 8; ++i) u[i] = H4[(size_t)c[i] * 16 + sub];
#pragma unroll
        for (int i = 0; i < 8; ++i) {
            float a[8];
            UNPACK8(a, u[i]);
#pragma unroll
            for (int j = 0; j < 8; ++j) acc[j] += a[j];
        }
        float pad = (float)(p + 8 - e);
#pragma unroll
        for (int j = 0; j < 8; ++j) acc[j] -= pad * t[j];
    }
}

// ---------------- K5: agg_mid fused with gemm2 ----------------
__global__ __launch_bounds__(256) void agg_gemm2(const uint4* __restrict__ H4,
                                                 const int* __restrict__ rowstart,
                                                 const int* __restrict__ rowend,
                                                 const int* __restrict__ colidx,
                                                 const float* __restrict__ dinv,
                                                 const float* __restrict__ b1,
                                                 const ushort* __restrict__ Wt2,
                                                 uint* __restrict__ Yb, int n) {
    __shared__ __align__(16) ushort sA[16][136];  // a1 (MFMA A source)
    __shared__ __align__(16) ushort sO[16][136];  // h2' staging
    int tid = threadIdx.x;
    int sub = tid & 15;
    int nl = tid >> 4;
    int node0 = blockIdx.x * 16;
    int node = node0 + nl;
    int nn = node < n ? node : n - 1;
    int s = rowstart[nn], e = rowend[nn];
    float di = dinv[nn];

    float acc[8];
    gather_q(H4, s, e, nn, sub, colidx, acc);
    {
        float4 c0 = ((const float4*)b1)[sub * 2];
        float4 c1 = ((const float4*)b1)[sub * 2 + 1];
        float f0 = fmaxf(fmaf(acc[0], di, c0.x), 0.f);
        float f1 = fmaxf(fmaf(acc[1], di, c0.y), 0.f);
        float f2 = fmaxf(fmaf(acc[2], di, c0.z), 0.f);
        float f3 = fmaxf(fmaf(acc[3], di, c0.w), 0.f);
        float f4 = fmaxf(fmaf(acc[4], di, c1.x), 0.f);
        float f5 = fmaxf(fmaf(acc[5], di, c1.y), 0.f);
        float f6 = fmaxf(fmaf(acc[6], di, c1.z), 0.f);
        float f7 = fmaxf(fmaf(acc[7], di, c1.w), 0.f);
        uint4 v;
        v.x = pack2(f0, f1); v.y = pack2(f2, f3);
        v.z = pack2(f4, f5); v.w = pack2(f6, f7);
        *(uint4*)&sA[nl][sub * 8] = v;
    }
    __syncthreads();

    // Phase B: h2' = dinv ⊙ (a1 @ W2) for this block's 16 rows
    const int wave = tid >> 6;
    const int lane = tid & 63;
    const int quad = lane >> 4, l16 = lane & 15;
    f32x4 acc2[2];
    acc2[0] = (f32x4){0.f, 0.f, 0.f, 0.f};
    acc2[1] = (f32x4){0.f, 0.f, 0.f, 0.f};
#pragma unroll
    for (int ks = 0; ks < 4; ++ks) {
        bf16x8 a = *(const bf16x8*)&sA[l16][ks * 32 + quad * 8];
#pragma unroll
        for (int t = 0; t < 2; ++t) {
            int nt = wave * 2 + t;
            bf16x8 b = *(const bf16x8*)&Wt2[(size_t)(nt * 16 + l16) * 128 + ks * 32 + quad * 8];
            acc2[t] = __builtin_amdgcn_mfma_f32_16x16x32_bf16(a, b, acc2[t], 0, 0, 0);
        }
    }
#pragma unroll
    for (int r = 0; r < 4; ++r) {
        int rr = node0 + quad * 4 + r;
        float dv = dinv[rr < n ? rr : n - 1];
#pragma unroll
        for (int t = 0; t < 2; ++t)
            sO[quad * 4 + r][(wave * 2 + t) * 16 + l16] = f2bf(acc2[t][r] * dv);
    }
    __syncthreads();

    {
        int row = tid >> 4, chunk = tid & 15;
        int rr = node0 + row;
        if (rr < n) {
            uint4 v = *(const uint4*)&sO[row][chunk * 8];
            *(uint4*)&Yb[(size_t)rr * 64 + chunk * 4] = v;
        }
    }
}

// ---------------- K6: agg_out + classifier ----------------
__global__ __launch_bounds__(256) void agg_out_q(const uint4* __restrict__ H4,
                                                 const int* __restrict__ rowstart,
                                                 const int* __restrict__ rowend,
                                                 const int* __restrict__ colidx,
                                                 const float* __restrict__ dinv,
                                                 const float* __restrict__ bias,
                                                 const float* __restrict__ Wc,
                                                 const float* __restrict__ bc,
                                                 float* __restrict__ out, int n) {
    __shared__ float sA[16][129];
    int tid = threadIdx.x;
    int sub = tid & 15;
    int nl = tid >> 4;
    int node = blockIdx.x * 16 + nl;
    int nn = node < n ? node : n - 1;
    int s = rowstart[nn], e = rowend[nn];
    float di = dinv[nn];

    float acc[8];
    gather_q(H4, s, e, nn, sub, colidx, acc);

    {
        float4 b0 = ((const float4*)bias)[sub * 2];
        float4 b1v = ((const float4*)bias)[sub * 2 + 1];
        float f[8];
        f[0] = fmaxf(fmaf(acc[0], di, b0.x), 0.f);
        f[1] = fmaxf(fmaf(acc[1], di, b0.y), 0.f);
        f[2] = fmaxf(fmaf(acc[2], di, b0.z), 0.f);
        f[3] = fmaxf(fmaf(acc[3], di, b0.w), 0.f);
        f[4] = fmaxf(fmaf(acc[4], di, b1v.x), 0.f);
        f[5] = fmaxf(fmaf(acc[5], di, b1v.y), 0.f);
        f[6] = fmaxf(fmaf(acc[6], di, b1v.z), 0.f);
        f[7] = fmaxf(fmaf(acc[7], di, b1v.w), 0.f);
#pragma unroll
        for (int j = 0; j < 8; ++j) sA[nl][sub * 8 + j] = f[j];
    }
    __syncthreads();

    int col = tid & 15;
    float p0 = 0.f, p1 = 0.f;
#pragma unroll 4
    for (int k = 0; k < 128; k += 2) {
        p0 = fmaf(sA[nl][k], Wc[k * 16 + col], p0);
        p1 = fmaf(sA[nl][k + 1], Wc[(k + 1) * 16 + col], p1);
    }
    if (node < n) out[(size_t)node * 16 + col] = p0 + p1 + bc[col];
}

// ---------------- launch ----------------

extern "C" void kernel_launch(void* const* d_in, const int* in_sizes, int n_in,
                              void* d_out, int out_size, void* d_ws, size_t ws_size,
                              hipStream_t stream) {
    const float* x  = (const float*)d_in[0];
    const int*   ei = (const int*)d_in[1];
    const float* W1 = (const float*)d_in[2];
    const float* b1 = (const float*)d_in[3];
    const float* W2 = (const float*)d_in[4];
    const float* b2 = (const float*)d_in[5];
    const float* Wc = (const float*)d_in[6];
    const float* bc = (const float*)d_in[7];
    float* out = (float*)d_out;

    const int n = in_sizes[0] / 128;  // 50000
    const int E = in_sizes[1] / 2;    // 1,600,000
    const int* src = ei;
    const int* dst = ei + E;
    const int nbuckets = (n + NPB - 1) / NPB;    // 196
    const int nsb = (n + 8191) / 8192;           // 7 super-buckets

    char* p = (char*)d_ws;
    auto alloc = [&](size_t bytes) {
        char* q = p;
        p += (bytes + 255) & ~(size_t)255;
        return q;
    };
    int*    bcursor  = (int*)alloc(256 * 4);
    int*    bcursor8 = (int*)alloc(64 * 4);
    int*    deg      = (int*)alloc((size_t)n * 4);
    int*    rowstart = (int*)alloc((size_t)n * 4);
    int*    rowend   = (int*)alloc((size_t)n * 4);
    float*  dinv     = (float*)alloc((size_t)n * 4);
    ushort* Wt1      = (ushort*)alloc(128 * 128 * 2);
    ushort* Wt2      = (ushort*)alloc(128 * 128 * 2);
    uint2*  pay8     = (uint2*)alloc((size_t)nsb * SCAP * 8);      // 15.6 MB
    uint*   pay      = (uint*)alloc((size_t)nbuckets * CAP * 4);   // 9.6 MB
    int*    colidx   = (int*)alloc((size_t)nbuckets * CAP * 4);    // 9.6 MB
    uint*   bufA     = (uint*)alloc((size_t)n * 64 * 4);  // bf16 h1'
    uint*   bufB     = (uint*)alloc((size_t)n * 64 * 4);  // bf16 h2'
    if ((size_t)(p - (char*)d_ws) > ws_size) return;

    const int ntile = (n + 63) / 64;           // 782 tiles
    const int gblocks = (ntile + 1) / 2;       // 391 gemm blocks (2 tiles each)
    const int aggb = (n + 15) / 16;            // 3125

    setup<<<64, 256, 0, stream>>>(bcursor, bcursor8, deg, W1, W2, Wt1, Wt2,
                                  n, nbuckets, nsb);
    bin8<<<512, 1024, 0, stream>>>(src, dst, bcursor8, deg, pay8, E);
    subsort<<<nsb * SBLK, 512, 0, stream>>>(pay8, bcursor8, bcursor, pay, nsb);
    build_gemm1<<<nbuckets + gblocks, 512, 0, stream>>>(pay, bcursor, rowstart, rowend,
                                                        dinv, colidx, x, Wt1, deg, bufA,
                                                        n, nbuckets, ntile);
    agg_gemm2<<<aggb, 256, 0, stream>>>((const uint4*)bufA, rowstart, rowend, colidx,
                                        dinv, b1, Wt2, bufB, n);
    agg_out_q<<<aggb, 256, 0, stream>>>((const uint4*)bufB, rowstart, rowend, colidx,
                                        dinv, b2, Wc, bc, out, n);
}